// Round 3
// baseline (42.534 us; speedup 1.0000x reference)
//
#include <hip/hip_runtime.h>
#include <hip/hip_bf16.h>

// CEKT: y_t = sigmoid([h_t|e_t|x] @ Wp + bp)
//   h_t = (1-g)*prev_h + g*tanh(comb @ Wh + bh),  g = sigmoid(comb @ Wq + bq)
//   comb = [e_t | r_t | prev_h]
// GAT branch is dead code w.r.t. y_t.
// Structure: 256 blocks x 256 threads, 16 rows/block, thread = 2 rows x 4 cols.
// 1 wave/SIMD (structural) -> latency hidden via 3-phase-lookahead register
// prefetch of weight float4s (ILP instead of TLP).

constexpr int DKc = 128, DHc = 128, DRc = 64, DEc = 128;
constexpr int K1 = DEc + DRc + DHc; // 320
constexpr int K2 = DHc + DEc + DKc; // 384
constexpr int BM = 16;              // rows per block

__device__ __forceinline__ void fma4(float4& acc, const float4 wv, const float s) {
    acc.x = fmaf(wv.x, s, acc.x);
    acc.y = fmaf(wv.y, s, acc.y);
    acc.z = fmaf(wv.z, s, acc.z);
    acc.w = fmaf(wv.w, s, acc.w);
}

__device__ __forceinline__ float sigmoidf_(float z) {
    return 1.0f / (1.0f + expf(-z));
}

struct W1b { float4 wq[4]; float4 wh[4]; };  // one 4-k phase of Wq+Wh
struct A1b { float4 a0, a1; };               // one 4-k phase of A (2 rows)
struct W2b { float4 wp[4]; };                // one 4-k phase of Wp

__global__ __launch_bounds__(256, 1) void cekt_fused(
    const float* __restrict__ x,
    const float* __restrict__ e_t,
    const float* __restrict__ r_t,
    const float* __restrict__ prev_h,
    const float* __restrict__ Wq, const float* __restrict__ bq,
    const float* __restrict__ Wh, const float* __restrict__ bh,
    const float* __restrict__ Wp, const float* __restrict__ bp,
    float* __restrict__ out)
{
    __shared__ float lds1[BM][K1];   // comb  = [e_t | r_t | prev_h]
    __shared__ float lds2[BM][K2];   // comb2 = [h_t | e_t | x]

    const int t = threadIdx.x;
    const int row0 = blockIdx.x * BM;

    // ---- stage comb (lds1) and the static 2/3 of comb2 (lds2) ----
    for (int i = t; i < BM * DEc; i += 256) {
        const int r = i >> 7, c = i & 127;
        const float v = e_t[(row0 + r) * DEc + c];
        lds1[r][c] = v;
        lds2[r][DHc + c] = v;
    }
    for (int i = t; i < BM * DRc; i += 256) {
        const int r = i >> 6, c = i & 63;
        lds1[r][DEc + c] = r_t[(row0 + r) * DRc + c];
    }
    for (int i = t; i < BM * DHc; i += 256) {
        const int r = i >> 7, c = i & 127;
        lds1[r][DEc + DRc + c] = prev_h[(row0 + r) * DHc + c];
    }
    for (int i = t; i < BM * DKc; i += 256) {
        const int r = i >> 7, c = i & 127;
        lds2[r][DHc + DEc + c] = x[(row0 + r) * DKc + c];
    }
    __syncthreads();

    const int colq = (t & 31) << 2;  // 0..124 step 4
    const int rg   = t >> 5;         // 0..7
    const int r0   = rg * 2, r1 = r0 + 1;

    // ================= GEMM1: g and cand over K1 (80 phases of 4 k) ========
    float4 ag0 = {0,0,0,0}, ag1 = {0,0,0,0};
    float4 ac0 = {0,0,0,0}, ac1 = {0,0,0,0};

    W1b wA, wB, wC, wD;
    A1b aE, aO;

    auto LDW1 = [&](W1b& b, int p) {
        const int k = p << 2;
#pragma unroll
        for (int kk = 0; kk < 4; ++kk) {
            b.wq[kk] = *(const float4*)&Wq[(k + kk) * 128 + colq];
            b.wh[kk] = *(const float4*)&Wh[(k + kk) * 128 + colq];
        }
    };
    auto LDA1 = [&](A1b& b, int p) {
        const int k = p << 2;
        b.a0 = *(const float4*)&lds1[r0][k];
        b.a1 = *(const float4*)&lds1[r1][k];
    };
    auto C1 = [&](const W1b& b, const A1b& a) {
#pragma unroll
        for (int kk = 0; kk < 4; ++kk) {
            const float s0 = (&a.a0.x)[kk];
            const float s1 = (&a.a1.x)[kk];
            fma4(ag0, b.wq[kk], s0);
            fma4(ag1, b.wq[kk], s1);
            fma4(ac0, b.wh[kk], s0);
            fma4(ac1, b.wh[kk], s1);
        }
    };

    constexpr int NP1 = K1 / 4;  // 80 (multiple of 4)
    LDW1(wA, 0); LDW1(wB, 1); LDW1(wC, 2); LDA1(aE, 0);
    for (int p = 0; p < NP1; p += 4) {
        LDW1(wD, p + 3);                 // p+3 <= 79 always
        LDA1(aO, p + 1);
        C1(wA, aE);
        if (p + 4 < NP1) { LDW1(wA, p + 4); }
        LDA1(aE, p + 2);
        C1(wB, aO);
        if (p + 5 < NP1) { LDW1(wB, p + 5); }
        LDA1(aO, p + 3);
        C1(wC, aE);
        if (p + 6 < NP1) { LDW1(wC, p + 6); }
        if (p + 4 < NP1) { LDA1(aE, p + 4); }
        C1(wD, aO);
    }

    const float4 bq4 = *(const float4*)&bq[colq];
    const float4 bh4 = *(const float4*)&bh[colq];
    const float4 ph0 = *(const float4*)&lds1[r0][DEc + DRc + colq];
    const float4 ph1 = *(const float4*)&lds1[r1][DEc + DRc + colq];

    float4 h0, h1;
    {
        float g, cd;
        g = sigmoidf_(ag0.x + bq4.x); cd = tanhf(ac0.x + bh4.x); h0.x = (1.0f - g) * ph0.x + g * cd;
        g = sigmoidf_(ag0.y + bq4.y); cd = tanhf(ac0.y + bh4.y); h0.y = (1.0f - g) * ph0.y + g * cd;
        g = sigmoidf_(ag0.z + bq4.z); cd = tanhf(ac0.z + bh4.z); h0.z = (1.0f - g) * ph0.z + g * cd;
        g = sigmoidf_(ag0.w + bq4.w); cd = tanhf(ac0.w + bh4.w); h0.w = (1.0f - g) * ph0.w + g * cd;
        g = sigmoidf_(ag1.x + bq4.x); cd = tanhf(ac1.x + bh4.x); h1.x = (1.0f - g) * ph1.x + g * cd;
        g = sigmoidf_(ag1.y + bq4.y); cd = tanhf(ac1.y + bh4.y); h1.y = (1.0f - g) * ph1.y + g * cd;
        g = sigmoidf_(ag1.z + bq4.z); cd = tanhf(ac1.z + bh4.z); h1.z = (1.0f - g) * ph1.z + g * cd;
        g = sigmoidf_(ag1.w + bq4.w); cd = tanhf(ac1.w + bh4.w); h1.w = (1.0f - g) * ph1.w + g * cd;
    }

    // h_t -> lds2[r][0:128]
    *(float4*)&lds2[r0][colq] = h0;
    *(float4*)&lds2[r1][colq] = h1;
    __syncthreads();

    // ================= GEMM2: y over K2 (96 phases of 4 k) =================
    float4 ay0 = {0,0,0,0}, ay1 = {0,0,0,0};
    W2b vA, vB, vC, vD;

    auto LDW2 = [&](W2b& b, int p) {
        const int k = p << 2;
#pragma unroll
        for (int kk = 0; kk < 4; ++kk) {
            b.wp[kk] = *(const float4*)&Wp[(k + kk) * 128 + colq];
        }
    };
    auto LDA2 = [&](A1b& b, int p) {
        const int k = p << 2;
        b.a0 = *(const float4*)&lds2[r0][k];
        b.a1 = *(const float4*)&lds2[r1][k];
    };
    auto C2 = [&](const W2b& b, const A1b& a) {
#pragma unroll
        for (int kk = 0; kk < 4; ++kk) {
            const float s0 = (&a.a0.x)[kk];
            const float s1 = (&a.a1.x)[kk];
            fma4(ay0, b.wp[kk], s0);
            fma4(ay1, b.wp[kk], s1);
        }
    };

    constexpr int NP2 = K2 / 4;  // 96 (multiple of 4)
    LDW2(vA, 0); LDW2(vB, 1); LDW2(vC, 2); LDA2(aE, 0);
    for (int p = 0; p < NP2; p += 4) {
        LDW2(vD, p + 3);                 // p+3 <= 95 always
        LDA2(aO, p + 1);
        C2(vA, aE);
        if (p + 4 < NP2) { LDW2(vA, p + 4); }
        LDA2(aE, p + 2);
        C2(vB, aO);
        if (p + 5 < NP2) { LDW2(vB, p + 5); }
        LDA2(aO, p + 3);
        C2(vC, aE);
        if (p + 6 < NP2) { LDW2(vC, p + 6); }
        if (p + 4 < NP2) { LDA2(aE, p + 4); }
        C2(vD, aO);
    }

    const float4 bp4 = *(const float4*)&bp[colq];
    float4 y0, y1;
    y0.x = sigmoidf_(ay0.x + bp4.x); y0.y = sigmoidf_(ay0.y + bp4.y);
    y0.z = sigmoidf_(ay0.z + bp4.z); y0.w = sigmoidf_(ay0.w + bp4.w);
    y1.x = sigmoidf_(ay1.x + bp4.x); y1.y = sigmoidf_(ay1.y + bp4.y);
    y1.z = sigmoidf_(ay1.z + bp4.z); y1.w = sigmoidf_(ay1.w + bp4.w);

    *(float4*)&out[(row0 + r0) * DHc + colq] = y0;
    *(float4*)&out[(row0 + r1) * DHc + colq] = y1;
}

extern "C" void kernel_launch(void* const* d_in, const int* in_sizes, int n_in,
                              void* d_out, int out_size, void* d_ws, size_t ws_size,
                              hipStream_t stream) {
    // setup_inputs order:
    // 0:x 1:adj 2:e_t 3:r_t 4:prev_h 5:W_heads 6:a_heads 7:W_out 8:a_out
    // 9:Wq_w 10:Wq_b 11:Wh_w 12:Wh_b 13:Wp_w 14:Wp_b
    const float* x      = (const float*)d_in[0];
    const float* e_t    = (const float*)d_in[2];
    const float* r_t    = (const float*)d_in[3];
    const float* prev_h = (const float*)d_in[4];
    const float* Wq_w   = (const float*)d_in[9];
    const float* Wq_b   = (const float*)d_in[10];
    const float* Wh_w   = (const float*)d_in[11];
    const float* Wh_b   = (const float*)d_in[12];
    const float* Wp_w   = (const float*)d_in[13];
    const float* Wp_b   = (const float*)d_in[14];
    float* out = (float*)d_out;

    const int N = 4096;
    dim3 grid(N / BM);   // 256 blocks
    dim3 block(256);
    hipLaunchKernelGGL(cekt_fused, grid, block, 0, stream,
                       x, e_t, r_t, prev_h,
                       Wq_w, Wq_b, Wh_w, Wh_b, Wp_w, Wp_b, out);
}

// Round 4
// 37.667 us; speedup vs baseline: 1.1292x; 1.1292x over previous
//
#include <hip/hip_runtime.h>
#include <hip/hip_bf16.h>

// CEKT: y_t = sigmoid([h_t|e_t|x] @ Wp + bp)
//   h_t = (1-g)*prev_h + g*tanh(comb @ Wh + bh),  g = sigmoid(comb @ Wq + bq)
//   comb = [e_t | r_t | prev_h]
// GAT branch is dead code w.r.t. y_t.
//
// Round-4 structure: k-split across waves.
//   block = 256 thr = 4 waves; each wave owns 1/4 of K; block covers 4 rows.
//   grid = 1024 blocks -> 4 blocks/CU, 16 waves/CU, 4 waves/SIMD (TLP hides
//   L2 latency that ILP could not at 1 wave/SIMD).
//   Partial sums reduced through LDS; activations fused in reduce phases.

constexpr int K1 = 320;  // DE + DR + DH
constexpr int K2 = 384;  // DH + DE + DK
constexpr int BMr = 4;   // rows per block
constexpr int CH1 = K1 / 4;  // 80  k per wave, GEMM1
constexpr int CH2 = K2 / 4;  // 96  k per wave, GEMM2

__device__ __forceinline__ void fma4(float4& acc, const float4 wv, const float s) {
    acc.x = fmaf(wv.x, s, acc.x);
    acc.y = fmaf(wv.y, s, acc.y);
    acc.z = fmaf(wv.z, s, acc.z);
    acc.w = fmaf(wv.w, s, acc.w);
}

__device__ __forceinline__ float sigmoidf_(float z) {
    return 1.0f / (1.0f + expf(-z));
}

__global__ __launch_bounds__(256, 4) void cekt_fused(
    const float* __restrict__ x,
    const float* __restrict__ e_t,
    const float* __restrict__ r_t,
    const float* __restrict__ prev_h,
    const float* __restrict__ Wq, const float* __restrict__ bq,
    const float* __restrict__ Wh, const float* __restrict__ bh,
    const float* __restrict__ Wp, const float* __restrict__ bp,
    float* __restrict__ out)
{
    __shared__ float lds1[BMr][K1];          // comb  = [e_t | r_t | prev_h]
    __shared__ float lds2[BMr][K2];          // comb2 = [h_t | e_t | x]
    __shared__ float part_g[4][BMr][128];    // per-wave partials (reused for y)
    __shared__ float part_c[4][BMr][128];

    const int t = threadIdx.x;
    const int row0 = blockIdx.x * BMr;

    // ---- stage A-operands (few float4 loads per thread) ----
    if (t < 128) {
        const int r = t >> 5, c = (t & 31) << 2;
        const float4 ev = *(const float4*)&e_t[(row0 + r) * 128 + c];
        *(float4*)&lds1[r][c] = ev;
        *(float4*)&lds2[r][128 + c] = ev;
        const float4 ph = *(const float4*)&prev_h[(row0 + r) * 128 + c];
        *(float4*)&lds1[r][192 + c] = ph;
        const float4 xv = *(const float4*)&x[(row0 + r) * 128 + c];
        *(float4*)&lds2[r][256 + c] = xv;
    } else {
        const int t2 = t - 128;
        if (t2 < 64) {
            const int r = t2 >> 4, c = (t2 & 15) << 2;
            *(float4*)&lds1[r][128 + c] = *(const float4*)&r_t[(row0 + r) * 64 + c];
        }
    }
    __syncthreads();

    const int w    = t >> 6;          // wave id = k-chunk id, 0..3
    const int lane = t & 63;
    const int rs   = lane >> 5;       // rowslot
    const int col  = (lane & 31) << 2;
    const int r0   = rs * 2, r1 = r0 + 1;

    // ================= GEMM1 partials over this wave's k-chunk =============
    {
        float4 ag0 = {0,0,0,0}, ag1 = {0,0,0,0};
        float4 ac0 = {0,0,0,0}, ac1 = {0,0,0,0};
        const int kbeg = w * CH1, kend = kbeg + CH1;
        for (int k = kbeg; k < kend; k += 4) {
            const float4 a0 = *(const float4*)&lds1[r0][k];
            const float4 a1 = *(const float4*)&lds1[r1][k];
#pragma unroll
            for (int kk = 0; kk < 4; ++kk) {
                const float4 wq = *(const float4*)&Wq[(k + kk) * 128 + col];
                const float4 wh = *(const float4*)&Wh[(k + kk) * 128 + col];
                const float s0 = (&a0.x)[kk];
                const float s1 = (&a1.x)[kk];
                fma4(ag0, wq, s0);
                fma4(ag1, wq, s1);
                fma4(ac0, wh, s0);
                fma4(ac1, wh, s1);
            }
        }
        *(float4*)&part_g[w][r0][col] = ag0;
        *(float4*)&part_g[w][r1][col] = ag1;
        *(float4*)&part_c[w][r0][col] = ac0;
        *(float4*)&part_c[w][r1][col] = ac1;
    }
    __syncthreads();

    // ---- reduce + gate + h_t -> lds2[:,0:128] ----
    if (t < 128) {
        const int r = t >> 5, c = (t & 31) << 2;
        float4 sg = *(const float4*)&part_g[0][r][c];
        float4 sc = *(const float4*)&part_c[0][r][c];
#pragma unroll
        for (int ww = 1; ww < 4; ++ww) {
            const float4 pg = *(const float4*)&part_g[ww][r][c];
            const float4 pc = *(const float4*)&part_c[ww][r][c];
            sg.x += pg.x; sg.y += pg.y; sg.z += pg.z; sg.w += pg.w;
            sc.x += pc.x; sc.y += pc.y; sc.z += pc.z; sc.w += pc.w;
        }
        const float4 bq4 = *(const float4*)&bq[c];
        const float4 bh4 = *(const float4*)&bh[c];
        const float4 ph  = *(const float4*)&lds1[r][192 + c];
        float4 h;
        float g, cd;
        g = sigmoidf_(sg.x + bq4.x); cd = tanhf(sc.x + bh4.x); h.x = (1.0f - g) * ph.x + g * cd;
        g = sigmoidf_(sg.y + bq4.y); cd = tanhf(sc.y + bh4.y); h.y = (1.0f - g) * ph.y + g * cd;
        g = sigmoidf_(sg.z + bq4.z); cd = tanhf(sc.z + bh4.z); h.z = (1.0f - g) * ph.z + g * cd;
        g = sigmoidf_(sg.w + bq4.w); cd = tanhf(sc.w + bh4.w); h.w = (1.0f - g) * ph.w + g * cd;
        *(float4*)&lds2[r][c] = h;
    }
    __syncthreads();

    // ================= GEMM2 partials over this wave's k-chunk =============
    {
        float4 ay0 = {0,0,0,0}, ay1 = {0,0,0,0};
        const int kbeg = w * CH2, kend = kbeg + CH2;
        for (int k = kbeg; k < kend; k += 4) {
            const float4 a0 = *(const float4*)&lds2[r0][k];
            const float4 a1 = *(const float4*)&lds2[r1][k];
#pragma unroll
            for (int kk = 0; kk < 4; ++kk) {
                const float4 wp = *(const float4*)&Wp[(k + kk) * 128 + col];
                const float s0 = (&a0.x)[kk];
                const float s1 = (&a1.x)[kk];
                fma4(ay0, wp, s0);
                fma4(ay1, wp, s1);
            }
        }
        *(float4*)&part_g[w][r0][col] = ay0;   // reuse part_g as y-partials
        *(float4*)&part_g[w][r1][col] = ay1;
    }
    __syncthreads();

    // ---- reduce + sigmoid -> out ----
    if (t < 128) {
        const int r = t >> 5, c = (t & 31) << 2;
        float4 sy = *(const float4*)&part_g[0][r][c];
#pragma unroll
        for (int ww = 1; ww < 4; ++ww) {
            const float4 py = *(const float4*)&part_g[ww][r][c];
            sy.x += py.x; sy.y += py.y; sy.z += py.z; sy.w += py.w;
        }
        const float4 bp4 = *(const float4*)&bp[c];
        float4 y;
        y.x = sigmoidf_(sy.x + bp4.x);
        y.y = sigmoidf_(sy.y + bp4.y);
        y.z = sigmoidf_(sy.z + bp4.z);
        y.w = sigmoidf_(sy.w + bp4.w);
        *(float4*)&out[(row0 + r) * 128 + c] = y;
    }
}

extern "C" void kernel_launch(void* const* d_in, const int* in_sizes, int n_in,
                              void* d_out, int out_size, void* d_ws, size_t ws_size,
                              hipStream_t stream) {
    // setup_inputs order:
    // 0:x 1:adj 2:e_t 3:r_t 4:prev_h 5:W_heads 6:a_heads 7:W_out 8:a_out
    // 9:Wq_w 10:Wq_b 11:Wh_w 12:Wh_b 13:Wp_w 14:Wp_b
    const float* x      = (const float*)d_in[0];
    const float* e_t    = (const float*)d_in[2];
    const float* r_t    = (const float*)d_in[3];
    const float* prev_h = (const float*)d_in[4];
    const float* Wq_w   = (const float*)d_in[9];
    const float* Wq_b   = (const float*)d_in[10];
    const float* Wh_w   = (const float*)d_in[11];
    const float* Wh_b   = (const float*)d_in[12];
    const float* Wp_w   = (const float*)d_in[13];
    const float* Wp_b   = (const float*)d_in[14];
    float* out = (float*)d_out;

    const int N = 4096;
    dim3 grid(N / BMr);   // 1024 blocks
    dim3 block(256);
    hipLaunchKernelGGL(cekt_fused, grid, block, 0, stream,
                       x, e_t, r_t, prev_h,
                       Wq_w, Wq_b, Wh_w, Wh_b, Wp_w, Wp_b, out);
}

// Round 5
// 35.420 us; speedup vs baseline: 1.2009x; 1.0635x over previous
//
#include <hip/hip_runtime.h>
#include <hip/hip_bf16.h>

// CEKT: y_t = sigmoid([h_t|e_t|x] @ Wp + bp)
//   h_t = (1-g)*prev_h + g*tanh(comb @ Wh + bh),  g = sigmoid(comb @ Wq + bq)
//   comb = [e_t | r_t | prev_h];  GAT branch is dead code w.r.t. y_t.
//
// Round-5 structure: weight staging in LDS (the r4 lesson: per-CU L1 weight
// traffic was the floor).  grid 256 = 1 block/CU; block 512 thr = 8 waves.
// Weights stream global->LDS once per CU via global_load_lds, double-buffered
// 32-k slabs.  Wave layout: 4 row-groups x 2 col-halves; lane = 2 rows x 2
// cols; half-waves read identical weight addresses (LDS broadcast).

constexpr int K1 = 320, K2 = 384;
constexpr int BM = 16;             // rows per block
constexpr int KS = 32;             // k-slab
constexpr int NS1 = K1 / KS;       // 10
constexpr int NS2 = K2 / KS;       // 12

__device__ __forceinline__ void fma2(float2& a, const float2 wv, const float s) {
    a.x = fmaf(wv.x, s, a.x);
    a.y = fmaf(wv.y, s, a.y);
}

__device__ __forceinline__ float sigmoidf_(float z) {
    return 1.0f / (1.0f + expf(-z));
}

__device__ __forceinline__ void gl_lds16(const float* g, float* l) {
    __builtin_amdgcn_global_load_lds(
        (const __attribute__((address_space(1))) void*)g,
        (__attribute__((address_space(3))) void*)l, 16, 0, 0);
}

__global__ __launch_bounds__(512, 1) void cekt_fused(
    const float* __restrict__ x,
    const float* __restrict__ e_t,
    const float* __restrict__ r_t,
    const float* __restrict__ prev_h,
    const float* __restrict__ Wq, const float* __restrict__ bq,
    const float* __restrict__ Wh, const float* __restrict__ bh,
    const float* __restrict__ Wp, const float* __restrict__ bp,
    float* __restrict__ out)
{
    __shared__ float lds1[BM][K1];          // comb  = [e_t | r_t | prev_h]  20 KB
    __shared__ float lds2[BM][K2];          // comb2 = [h_t | e_t | x]       24 KB
    __shared__ float wbuf[2][2][KS * 128];  // weight slabs, dbuf x {matA,matB} 64 KB

    const int t = threadIdx.x;
    const int row0 = blockIdx.x * BM;
    const int w = t >> 6, lane = t & 63;
    const int rw = w & 3;            // row group 0..3 (4 rows each)
    const int ch = w >> 2;           // col half 0..1
    const int hh = lane >> 5;        // half-wave: row pair select
    const int cg = lane & 31;
    const int col = ch * 64 + cg * 2;      // 2 cols per lane
    const int r0 = rw * 4 + hh * 2, r1 = r0 + 1;

    // ---- stage A-operands (vectorized float4) ----
    for (int i = t; i < BM * 32; i += 512) {      // 512 float4 per array
        const int r = i >> 5, c = (i & 31) << 2;
        const float4 ev = *(const float4*)&e_t[(row0 + r) * 128 + c];
        *(float4*)&lds1[r][c] = ev;
        *(float4*)&lds2[r][128 + c] = ev;
        const float4 ph = *(const float4*)&prev_h[(row0 + r) * 128 + c];
        *(float4*)&lds1[r][192 + c] = ph;
        const float4 xv = *(const float4*)&x[(row0 + r) * 128 + c];
        *(float4*)&lds2[r][256 + c] = xv;
    }
    for (int i = t; i < BM * 16; i += 512) {      // 256 float4 of r_t
        const int r = i >> 4, c = (i & 15) << 2;
        *(float4*)&lds1[r][128 + c] = *(const float4*)&r_t[(row0 + r) * 64 + c];
    }

    // staging lambdas: slab s of Wq+Wh (or Wp) -> wbuf[b]
    // slab = 32 rows x 128 cols = 16 KB/mat = 16 chunks of 1 KB; 8 waves x 2.
    auto stage1 = [&](int s, int b) {
        const int k0s = s * KS * 128;
        const int cb = w * 512;              // 2 chunks of 256 floats per wave
#pragma unroll
        for (int j = 0; j < 2; ++j) {
            const int o = cb + j * 256;
            gl_lds16(Wq + k0s + o + lane * 4, &wbuf[b][0][o]);
            gl_lds16(Wh + k0s + o + lane * 4, &wbuf[b][1][o]);
        }
    };
    auto stageP = [&](int s, int b) {
        const int k0s = s * KS * 128;
        const int cb = w * 512;
#pragma unroll
        for (int j = 0; j < 2; ++j) {
            const int o = cb + j * 256;
            gl_lds16(Wp + k0s + o + lane * 4, &wbuf[b][0][o]);
        }
    };

    stage1(0, 0);
    __syncthreads();   // drains lgkmcnt (A stores) + vmcnt (slab 0 DMA)

    // ================= GEMM1: g,cand accumulate over K1 ====================
    float2 ag0 = {0, 0}, ag1 = {0, 0}, ac0 = {0, 0}, ac1 = {0, 0};
    int buf = 0;
    for (int s = 0; s < NS1; ++s) {
        if (s + 1 < NS1) stage1(s + 1, buf ^ 1);
        else             stageP(0, buf ^ 1);    // buf^1 == 0 at s == 9
        const float* wqb = &wbuf[buf][0][0];
        const float* whb = &wbuf[buf][1][0];
        const int k0 = s * KS;
#pragma unroll
        for (int kg = 0; kg < KS / 4; ++kg) {
            const int k = kg * 4;
            const float4 a0 = *(const float4*)&lds1[r0][k0 + k];
            const float4 a1 = *(const float4*)&lds1[r1][k0 + k];
#pragma unroll
            for (int kk = 0; kk < 4; ++kk) {
                const float2 wq = *(const float2*)&wqb[(k + kk) * 128 + col];
                const float2 wh = *(const float2*)&whb[(k + kk) * 128 + col];
                const float s0 = (&a0.x)[kk];
                const float s1 = (&a1.x)[kk];
                fma2(ag0, wq, s0);
                fma2(ag1, wq, s1);
                fma2(ac0, wh, s0);
                fma2(ac1, wh, s1);
            }
        }
        __syncthreads();
        buf ^= 1;
    }
    // buf == 0 here; wbuf[0][0] holds Wp slab 0.

    // ---- gate + h_t -> lds2[:,0:128] (full sums, no reduction needed) ----
    {
        const float2 bq2 = *(const float2*)&bq[col];
        const float2 bh2 = *(const float2*)&bh[col];
        const float2 p0 = *(const float2*)&lds1[r0][192 + col];
        const float2 p1 = *(const float2*)&lds1[r1][192 + col];
        float2 h0, h1;
        float g, cd;
        g = sigmoidf_(ag0.x + bq2.x); cd = tanhf(ac0.x + bh2.x); h0.x = (1.0f - g) * p0.x + g * cd;
        g = sigmoidf_(ag0.y + bq2.y); cd = tanhf(ac0.y + bh2.y); h0.y = (1.0f - g) * p0.y + g * cd;
        g = sigmoidf_(ag1.x + bq2.x); cd = tanhf(ac1.x + bh2.x); h1.x = (1.0f - g) * p1.x + g * cd;
        g = sigmoidf_(ag1.y + bq2.y); cd = tanhf(ac1.y + bh2.y); h1.y = (1.0f - g) * p1.y + g * cd;
        *(float2*)&lds2[r0][col] = h0;
        *(float2*)&lds2[r1][col] = h1;
    }
    __syncthreads();

    // ================= GEMM2: y accumulate over K2 =========================
    float2 ay0 = {0, 0}, ay1 = {0, 0};
    for (int s = 0; s < NS2; ++s) {
        if (s + 1 < NS2) stageP(s + 1, buf ^ 1);
        const float* wpb = &wbuf[buf][0][0];
        const int k0 = s * KS;
#pragma unroll
        for (int kg = 0; kg < KS / 4; ++kg) {
            const int k = kg * 4;
            const float4 a0 = *(const float4*)&lds2[r0][k0 + k];
            const float4 a1 = *(const float4*)&lds2[r1][k0 + k];
#pragma unroll
            for (int kk = 0; kk < 4; ++kk) {
                const float2 wp = *(const float2*)&wpb[(k + kk) * 128 + col];
                const float s0 = (&a0.x)[kk];
                const float s1 = (&a1.x)[kk];
                fma2(ay0, wp, s0);
                fma2(ay1, wp, s1);
            }
        }
        if (s + 1 < NS2) { __syncthreads(); buf ^= 1; }
    }

    // ---- sigmoid -> out ----
    {
        const float2 bp2 = *(const float2*)&bp[col];
        float2 y0, y1;
        y0.x = sigmoidf_(ay0.x + bp2.x);
        y0.y = sigmoidf_(ay0.y + bp2.y);
        y1.x = sigmoidf_(ay1.x + bp2.x);
        y1.y = sigmoidf_(ay1.y + bp2.y);
        *(float2*)&out[(row0 + r0) * 128 + col] = y0;
        *(float2*)&out[(row0 + r1) * 128 + col] = y1;
    }
}

extern "C" void kernel_launch(void* const* d_in, const int* in_sizes, int n_in,
                              void* d_out, int out_size, void* d_ws, size_t ws_size,
                              hipStream_t stream) {
    // setup_inputs order:
    // 0:x 1:adj 2:e_t 3:r_t 4:prev_h 5:W_heads 6:a_heads 7:W_out 8:a_out
    // 9:Wq_w 10:Wq_b 11:Wh_w 12:Wh_b 13:Wp_w 14:Wp_b
    const float* x      = (const float*)d_in[0];
    const float* e_t    = (const float*)d_in[2];
    const float* r_t    = (const float*)d_in[3];
    const float* prev_h = (const float*)d_in[4];
    const float* Wq_w   = (const float*)d_in[9];
    const float* Wq_b   = (const float*)d_in[10];
    const float* Wh_w   = (const float*)d_in[11];
    const float* Wh_b   = (const float*)d_in[12];
    const float* Wp_w   = (const float*)d_in[13];
    const float* Wp_b   = (const float*)d_in[14];
    float* out = (float*)d_out;

    const int N = 4096;
    dim3 grid(N / BM);   // 256 blocks = 1 per CU
    dim3 block(512);     // 8 waves
    hipLaunchKernelGGL(cekt_fused, grid, block, 0, stream,
                       x, e_t, r_t, prev_h,
                       Wq_w, Wq_b, Wh_w, Wh_b, Wp_w, Wp_b, out);
}

// Round 6
// 21.444 us; speedup vs baseline: 1.9835x; 1.6517x over previous
//
#include <hip/hip_runtime.h>
#include <hip/hip_bf16.h>

// CEKT: y_t = sigmoid([h_t|e_t|x] @ Wp + bp)
//   h_t = (1-g)*prev_h + g*tanh(comb @ Wh + bh),  g = sigmoid(comb @ Wq + bq)
//   comb = [e_t | r_t | prev_h];  GAT branch is dead code w.r.t. y_t.
//
// Round-6: move FLOPs to the MFMA pipe. fp32 emulated as split-bf16:
//   x*w = xh*wh + xh*wl + xl*wh   (xl = x - bf16(x); error ~2^-17 rel)
// prep_w: Wq/Wh/Wp fp32 -> hi/lo bf16 in MFMA B-frag layout in d_ws.
// cekt_mfma: 256 blocks(=CUs) x 512 thr (8 waves); block = 16 rows; wave =
// one 16-col tile for g,c (phase1) and y (phase2). A staged in LDS in A-frag
// layout; B streamed global->VGPR (L2-resident). mfma_f32_16x16x32_bf16;
// C layout (m89-verified): col=lane&15, row=(lane>>4)*4+reg.

typedef short s16x8 __attribute__((ext_vector_type(8)));
typedef float f32x4 __attribute__((ext_vector_type(4)));

constexpr int NKQ = 10;  // K1=320 -> 10 ksteps of 32
constexpr int NKP = 12;  // K2=384 -> 12 ksteps of 32
constexpr int CH_Q = 0, CH_H = 80, CH_P = 160, NCHUNK = 256;  // 16B-chunk*64 units
constexpr int LO_OFF = NCHUNK * 64;  // offset (in 16B units) of lo region

__device__ __forceinline__ ushort bf16_rne(float f) {
    union { float f; uint u; } a; a.f = f;
    return (ushort)((a.u + 0x7FFFu + ((a.u >> 16) & 1u)) >> 16);
}
__device__ __forceinline__ float bf16_to_f(ushort h) {
    union { uint u; float f; } b; b.u = ((uint)h) << 16;
    return b.f;
}
__device__ __forceinline__ void split2(float f, ushort& hi, ushort& lo) {
    hi = bf16_rne(f);
    lo = bf16_rne(f - bf16_to_f(hi));
}

// ---------------- prep: weights -> B-frag hi/lo bf16 in d_ws ----------------
// elem (chunk, l, j):  W[s*32 + (l>>4)*8 + j][ct*16 + (l&15)]
// chunk = matoff + ct*nk + s ; stored at 16B unit (chunk*64 + l), j within.
__global__ __launch_bounds__(256) void prep_w(
    const float* __restrict__ Wq, const float* __restrict__ Wh,
    const float* __restrict__ Wp, ushort* __restrict__ ws)
{
    const int gid = blockIdx.x * 256 + threadIdx.x;  // 0..16383
    const int chunk = gid >> 6;
    const int l = gid & 63;
    const float* W;
    int s, ct;
    if (chunk < CH_H)      { W = Wq; ct = chunk / NKQ;            s = chunk % NKQ; }
    else if (chunk < CH_P) { W = Wh; ct = (chunk - CH_H) / NKQ;   s = (chunk - CH_H) % NKQ; }
    else                   { W = Wp; ct = (chunk - CH_P) / NKP;   s = (chunk - CH_P) % NKP; }
    const int col = ct * 16 + (l & 15);
    const int kbase = s * 32 + (l >> 4) * 8;
    ushort hi[8], lo[8];
#pragma unroll
    for (int j = 0; j < 8; ++j)
        split2(W[(kbase + j) * 128 + col], hi[j], lo[j]);
    uint4* o = (uint4*)ws + (chunk * 64 + l);
    *o = *(const uint4*)hi;
    *(o + LO_OFF) = *(const uint4*)lo;
}

// ---------------- main ----------------
__global__ __launch_bounds__(512, 1) void cekt_mfma(
    const float* __restrict__ x,
    const float* __restrict__ e_t,
    const float* __restrict__ r_t,
    const float* __restrict__ prev_h,
    const float* __restrict__ bq,
    const float* __restrict__ bh,
    const float* __restrict__ bp,
    const ushort* __restrict__ ws,
    float* __restrict__ out)
{
    __shared__ alignas(16) ushort A1h[NKQ * 64 * 8], A1l[NKQ * 64 * 8];
    __shared__ alignas(16) ushort A2h[NKP * 64 * 8], A2l[NKP * 64 * 8];
    __shared__ float hf[16][128];

    const int t = threadIdx.x;
    const int row0 = blockIdx.x * 16;
    const int w = t >> 6, lane = t & 63;

    // ---- phase 0: stage A1 (comb1) + A2 static part (e_t | x) as hi/lo ----
    {
        const int l = t >> 3, j = t & 7;
        const int row = l & 15;
        const int kk = (l >> 4) * 8 + j;   // 0..31 within a kstep
#pragma unroll
        for (int s = 0; s < NKQ; ++s) {
            const int k = s * 32 + kk;     // 0..319
            float v;
            if (k < 128)      v = e_t[(row0 + row) * 128 + k];
            else if (k < 192) v = r_t[(row0 + row) * 64 + (k - 128)];
            else              v = prev_h[(row0 + row) * 128 + (k - 192)];
            ushort hi, lo; split2(v, hi, lo);
            A1h[(s * 64 + l) * 8 + j] = hi;
            A1l[(s * 64 + l) * 8 + j] = lo;
        }
#pragma unroll
        for (int s = 4; s < NKP; ++s) {
            const int k = s * 32 + kk;     // 128..383
            const float v = (k < 256) ? e_t[(row0 + row) * 128 + (k - 128)]
                                      : x[(row0 + row) * 128 + (k - 256)];
            ushort hi, lo; split2(v, hi, lo);
            A2h[(s * 64 + l) * 8 + j] = hi;
            A2l[(s * 64 + l) * 8 + j] = lo;
        }
    }
    __syncthreads();

    const s16x8* whv = (const s16x8*)ws;
    const s16x8* wlv = whv + LO_OFF;

    // ---- phase 1: g, cand for col-tile w ----
    f32x4 gacc = {0, 0, 0, 0}, cacc = {0, 0, 0, 0};
#pragma unroll
    for (int s = 0; s < NKQ; ++s) {
        const s16x8 aH = *(const s16x8*)&A1h[(s * 64 + lane) * 8];
        const s16x8 aL = *(const s16x8*)&A1l[(s * 64 + lane) * 8];
        const int cq = (CH_Q + w * NKQ + s) * 64 + lane;
        const int cc = (CH_H + w * NKQ + s) * 64 + lane;
        const s16x8 qH = whv[cq];
        const s16x8 qL = wlv[cq];
        const s16x8 cH = whv[cc];
        const s16x8 cL = wlv[cc];
        gacc = __builtin_amdgcn_mfma_f32_16x16x32_bf16(aH, qH, gacc, 0, 0, 0);
        cacc = __builtin_amdgcn_mfma_f32_16x16x32_bf16(aH, cH, cacc, 0, 0, 0);
        gacc = __builtin_amdgcn_mfma_f32_16x16x32_bf16(aH, qL, gacc, 0, 0, 0);
        cacc = __builtin_amdgcn_mfma_f32_16x16x32_bf16(aH, cL, cacc, 0, 0, 0);
        gacc = __builtin_amdgcn_mfma_f32_16x16x32_bf16(aL, qH, gacc, 0, 0, 0);
        cacc = __builtin_amdgcn_mfma_f32_16x16x32_bf16(aL, cH, cacc, 0, 0, 0);
    }

    // ---- epilogue 1: gate + h_t -> hf ----
    {
        const int colL = lane & 15, rg = lane >> 4;
        const int col = w * 16 + colL;
        const float bqv = bq[col], bhv = bh[col];
#pragma unroll
        for (int i = 0; i < 4; ++i) {
            const int row = rg * 4 + i;
            const float ph = prev_h[(row0 + row) * 128 + col];
            const float g = 1.0f / (1.0f + expf(-(gacc[i] + bqv)));
            const float cd = tanhf(cacc[i] + bhv);
            hf[row][col] = (1.0f - g) * ph + g * cd;
        }
    }
    __syncthreads();

    // ---- restage h into A2 ksteps 0..3 ----
    {
        const int l = t >> 3, j = t & 7;
        const int row = l & 15;
        const int kk = (l >> 4) * 8 + j;
#pragma unroll
        for (int s = 0; s < 4; ++s) {
            ushort hi, lo; split2(hf[row][s * 32 + kk], hi, lo);
            A2h[(s * 64 + l) * 8 + j] = hi;
            A2l[(s * 64 + l) * 8 + j] = lo;
        }
    }
    __syncthreads();

    // ---- phase 2: y for col-tile w ----
    f32x4 yacc = {0, 0, 0, 0};
#pragma unroll
    for (int s = 0; s < NKP; ++s) {
        const s16x8 aH = *(const s16x8*)&A2h[(s * 64 + lane) * 8];
        const s16x8 aL = *(const s16x8*)&A2l[(s * 64 + lane) * 8];
        const int cp = (CH_P + w * NKP + s) * 64 + lane;
        const s16x8 pH = whv[cp];
        const s16x8 pL = wlv[cp];
        yacc = __builtin_amdgcn_mfma_f32_16x16x32_bf16(aH, pH, yacc, 0, 0, 0);
        yacc = __builtin_amdgcn_mfma_f32_16x16x32_bf16(aH, pL, yacc, 0, 0, 0);
        yacc = __builtin_amdgcn_mfma_f32_16x16x32_bf16(aL, pH, yacc, 0, 0, 0);
    }
    {
        const int colL = lane & 15, rg = lane >> 4;
        const int col = w * 16 + colL;
        const float bpv = bp[col];
#pragma unroll
        for (int i = 0; i < 4; ++i) {
            const int row = rg * 4 + i;
            out[(row0 + row) * 128 + col] = 1.0f / (1.0f + expf(-(yacc[i] + bpv)));
        }
    }
}

extern "C" void kernel_launch(void* const* d_in, const int* in_sizes, int n_in,
                              void* d_out, int out_size, void* d_ws, size_t ws_size,
                              hipStream_t stream) {
    // setup_inputs order:
    // 0:x 1:adj 2:e_t 3:r_t 4:prev_h 5:W_heads 6:a_heads 7:W_out 8:a_out
    // 9:Wq_w 10:Wq_b 11:Wh_w 12:Wh_b 13:Wp_w 14:Wp_b
    const float* x      = (const float*)d_in[0];
    const float* e_t    = (const float*)d_in[2];
    const float* r_t    = (const float*)d_in[3];
    const float* prev_h = (const float*)d_in[4];
    const float* Wq_w   = (const float*)d_in[9];
    const float* Wq_b   = (const float*)d_in[10];
    const float* Wh_w   = (const float*)d_in[11];
    const float* Wh_b   = (const float*)d_in[12];
    const float* Wp_w   = (const float*)d_in[13];
    const float* Wp_b   = (const float*)d_in[14];
    float* out  = (float*)d_out;
    ushort* ws  = (ushort*)d_ws;   // 262144 bf16 = 512 KB used

    hipLaunchKernelGGL(prep_w, dim3(64), dim3(256), 0, stream,
                       Wq_w, Wh_w, Wp_w, ws);
    hipLaunchKernelGGL(cekt_mfma, dim3(256), dim3(512), 0, stream,
                       x, e_t, r_t, prev_h, Wq_b, Wh_b, Wp_b, ws, out);
}

// Round 7
// 20.754 us; speedup vs baseline: 2.0494x; 1.0332x over previous
//
#include <hip/hip_runtime.h>
#include <hip/hip_bf16.h>

// CEKT: y_t = sigmoid([h_t|e_t|x] @ Wp + bp)
//   h_t = (1-g)*prev_h + g*tanh(comb @ Wh + bh),  g = sigmoid(comb @ Wq + bq)
//   comb = [e_t | r_t | prev_h];  GAT branch is dead code w.r.t. y_t.
//
// Round-7: r6 MFMA structure + k-split TLP.
//   block = 1024 thr = 16 waves = 4 waves/SIMD; wave = (ct 0..7, kh 0..1).
//   Phase1: each wave 5 ksteps (30 MFMA), kh1 partials reduced via LDS.
//   Overlap: kh0 does gate epilogue while kh1 runs phase2 static ksteps.
//   fp32 as split-bf16 3-term: x*w = xh*wh + xh*wl + xl*wh.

typedef short s16x8 __attribute__((ext_vector_type(8)));
typedef float f32x4 __attribute__((ext_vector_type(4)));

constexpr int NKQ = 10;  // K1=320 -> 10 ksteps of 32
constexpr int NKP = 12;  // K2=384 -> 12 ksteps of 32
constexpr int CH_Q = 0, CH_H = 80, CH_P = 160, NCHUNK = 256;
constexpr int LO_OFF = NCHUNK * 64;  // 16B units between hi and lo regions

__device__ __forceinline__ ushort bf16_rne(float f) {
    union { float f; uint u; } a; a.f = f;
    return (ushort)((a.u + 0x7FFFu + ((a.u >> 16) & 1u)) >> 16);
}
__device__ __forceinline__ float bf16_to_f(ushort h) {
    union { uint u; float f; } b; b.u = ((uint)h) << 16;
    return b.f;
}
__device__ __forceinline__ void split2(float f, ushort& hi, ushort& lo) {
    hi = bf16_rne(f);
    lo = bf16_rne(f - bf16_to_f(hi));
}

// ---------------- prep: weights -> B-frag hi/lo bf16 in d_ws ----------------
// elem (chunk, l, j):  W[s*32 + (l>>4)*8 + j][ct*16 + (l&15)]
__global__ __launch_bounds__(64) void prep_w(
    const float* __restrict__ Wq, const float* __restrict__ Wh,
    const float* __restrict__ Wp, ushort* __restrict__ ws)
{
    const int gid = blockIdx.x * 64 + threadIdx.x;  // 0..16383
    const int chunk = gid >> 6;
    const int l = gid & 63;
    const float* W;
    int s, ct;
    if (chunk < CH_H)      { W = Wq; ct = chunk / NKQ;          s = chunk % NKQ; }
    else if (chunk < CH_P) { W = Wh; ct = (chunk - CH_H) / NKQ; s = (chunk - CH_H) % NKQ; }
    else                   { W = Wp; ct = (chunk - CH_P) / NKP; s = (chunk - CH_P) % NKP; }
    const int col = ct * 16 + (l & 15);
    const int kbase = s * 32 + (l >> 4) * 8;
    ushort hi[8], lo[8];
#pragma unroll
    for (int j = 0; j < 8; ++j)
        split2(W[(kbase + j) * 128 + col], hi[j], lo[j]);
    uint4* o = (uint4*)ws + (chunk * 64 + l);
    *o = *(const uint4*)hi;
    *(o + LO_OFF) = *(const uint4*)lo;
}

// ---------------- main ----------------
__global__ __launch_bounds__(1024, 1) void cekt_mfma(
    const float* __restrict__ x,
    const float* __restrict__ e_t,
    const float* __restrict__ r_t,
    const float* __restrict__ prev_h,
    const float* __restrict__ bq,
    const float* __restrict__ bh,
    const float* __restrict__ bp,
    const ushort* __restrict__ ws,
    float* __restrict__ out)
{
    __shared__ alignas(16) ushort A1h[NKQ * 64 * 8], A1l[NKQ * 64 * 8];
    __shared__ alignas(16) ushort A2h[NKP * 64 * 8], A2l[NKP * 64 * 8];
    __shared__ float hf[16][128];
    __shared__ f32x4 p1g[8][64], p1c[8][64], p2y[8][64];

    const int t = threadIdx.x;
    const int row0 = blockIdx.x * 16;
    const int w = t >> 6, lane = t & 63;
    const int ct = w & 7, kh = w >> 3;

    // ---- stage A1 (comb1), coalesced float4 per row ----
    for (int i = t; i < 1280; i += 1024) {
        const int row = i / 80, kq4 = i - row * 80;
        const int k0 = kq4 * 4;
        float4 v;
        if (k0 < 128)      v = *(const float4*)&e_t[(row0 + row) * 128 + k0];
        else if (k0 < 192) v = *(const float4*)&r_t[(row0 + row) * 64 + (k0 - 128)];
        else               v = *(const float4*)&prev_h[(row0 + row) * 128 + (k0 - 192)];
        const int s = k0 >> 5, q = (k0 >> 3) & 3, j0 = k0 & 7;
        const int base = (s * 64 + q * 16 + row) * 8 + j0;
        ushort hi4[4], lo4[4];
        split2(v.x, hi4[0], lo4[0]); split2(v.y, hi4[1], lo4[1]);
        split2(v.z, hi4[2], lo4[2]); split2(v.w, hi4[3], lo4[3]);
        *(uint2*)&A1h[base] = *(const uint2*)hi4;
        *(uint2*)&A1l[base] = *(const uint2*)lo4;
    }
    // ---- stage A2 static part (s=4..11: e_t | x), one float4 per thread ----
    {
        const int row = t >> 6, kr = t & 63;
        const int k0 = 128 + kr * 4;            // 128..380
        const float4 v = (k0 < 256)
            ? *(const float4*)&e_t[(row0 + row) * 128 + (k0 - 128)]
            : *(const float4*)&x[(row0 + row) * 128 + (k0 - 256)];
        const int s = k0 >> 5, q = (k0 >> 3) & 3, j0 = k0 & 7;
        const int base = (s * 64 + q * 16 + row) * 8 + j0;
        ushort hi4[4], lo4[4];
        split2(v.x, hi4[0], lo4[0]); split2(v.y, hi4[1], lo4[1]);
        split2(v.z, hi4[2], lo4[2]); split2(v.w, hi4[3], lo4[3]);
        *(uint2*)&A2h[base] = *(const uint2*)hi4;
        *(uint2*)&A2l[base] = *(const uint2*)lo4;
    }
    __syncthreads();

    const s16x8* whv = (const s16x8*)ws;
    const s16x8* wlv = whv + LO_OFF;

    // ---- phase 1: g,cand partials over this k-half (5 ksteps) ----
    f32x4 gacc = {0, 0, 0, 0}, cacc = {0, 0, 0, 0};
    {
        const int sbeg = kh * 5;
#pragma unroll
        for (int si = 0; si < 5; ++si) {
            const int s = sbeg + si;
            const s16x8 aH = *(const s16x8*)&A1h[(s * 64 + lane) * 8];
            const s16x8 aL = *(const s16x8*)&A1l[(s * 64 + lane) * 8];
            const int cq = (CH_Q + ct * NKQ + s) * 64 + lane;
            const int cc = (CH_H + ct * NKQ + s) * 64 + lane;
            const s16x8 qH = whv[cq], qL = wlv[cq];
            const s16x8 cH = whv[cc], cL = wlv[cc];
            gacc = __builtin_amdgcn_mfma_f32_16x16x32_bf16(aH, qH, gacc, 0, 0, 0);
            cacc = __builtin_amdgcn_mfma_f32_16x16x32_bf16(aH, cH, cacc, 0, 0, 0);
            gacc = __builtin_amdgcn_mfma_f32_16x16x32_bf16(aH, qL, gacc, 0, 0, 0);
            cacc = __builtin_amdgcn_mfma_f32_16x16x32_bf16(aH, cL, cacc, 0, 0, 0);
            gacc = __builtin_amdgcn_mfma_f32_16x16x32_bf16(aL, qH, gacc, 0, 0, 0);
            cacc = __builtin_amdgcn_mfma_f32_16x16x32_bf16(aL, cH, cacc, 0, 0, 0);
        }
    }
    if (kh) { p1g[ct][lane] = gacc; p1c[ct][lane] = cacc; }
    __syncthreads();

    f32x4 yacc = {0, 0, 0, 0};
    if (!kh) {
        // ---- reduce + gate epilogue -> hf ----
        gacc += p1g[ct][lane];
        cacc += p1c[ct][lane];
        const int colL = lane & 15, rg = lane >> 4;
        const int col = ct * 16 + colL;
        const float bqv = bq[col], bhv = bh[col];
#pragma unroll
        for (int i2 = 0; i2 < 4; ++i2) {
            const int row = rg * 4 + i2;
            const float ph = prev_h[(row0 + row) * 128 + col];
            const float g = 1.0f / (1.0f + expf(-(gacc[i2] + bqv)));
            const float cd = tanhf(cacc[i2] + bhv);
            hf[row][col] = (1.0f - g) * ph + g * cd;
        }
    } else {
        // ---- phase 2 partials over static ksteps s=6..11 (overlaps epi1) ----
#pragma unroll
        for (int si = 0; si < 6; ++si) {
            const int s = 6 + si;
            const s16x8 aH = *(const s16x8*)&A2h[(s * 64 + lane) * 8];
            const s16x8 aL = *(const s16x8*)&A2l[(s * 64 + lane) * 8];
            const int cp = (CH_P + ct * NKP + s) * 64 + lane;
            const s16x8 pH = whv[cp], pL = wlv[cp];
            yacc = __builtin_amdgcn_mfma_f32_16x16x32_bf16(aH, pH, yacc, 0, 0, 0);
            yacc = __builtin_amdgcn_mfma_f32_16x16x32_bf16(aH, pL, yacc, 0, 0, 0);
            yacc = __builtin_amdgcn_mfma_f32_16x16x32_bf16(aL, pH, yacc, 0, 0, 0);
        }
        p2y[ct][lane] = yacc;
    }
    __syncthreads();

    // ---- restage h_t -> A2 ksteps 0..3 ----
    if (t < 512) {
        const int row = t >> 5, kr = t & 31;
        const int k0 = kr * 4;
        const float4 v = *(const float4*)&hf[row][k0];
        const int s = k0 >> 5, q = (k0 >> 3) & 3, j0 = k0 & 7;
        const int base = (s * 64 + q * 16 + row) * 8 + j0;
        ushort hi4[4], lo4[4];
        split2(v.x, hi4[0], lo4[0]); split2(v.y, hi4[1], lo4[1]);
        split2(v.z, hi4[2], lo4[2]); split2(v.w, hi4[3], lo4[3]);
        *(uint2*)&A2h[base] = *(const uint2*)hi4;
        *(uint2*)&A2l[base] = *(const uint2*)lo4;
    }
    __syncthreads();

    // ---- phase 2 remainder (s=0..5) + output, kh0 waves ----
    if (!kh) {
        yacc = p2y[ct][lane];
#pragma unroll
        for (int si = 0; si < 6; ++si) {
            const int s = si;
            const s16x8 aH = *(const s16x8*)&A2h[(s * 64 + lane) * 8];
            const s16x8 aL = *(const s16x8*)&A2l[(s * 64 + lane) * 8];
            const int cp = (CH_P + ct * NKP + s) * 64 + lane;
            const s16x8 pH = whv[cp], pL = wlv[cp];
            yacc = __builtin_amdgcn_mfma_f32_16x16x32_bf16(aH, pH, yacc, 0, 0, 0);
            yacc = __builtin_amdgcn_mfma_f32_16x16x32_bf16(aH, pL, yacc, 0, 0, 0);
            yacc = __builtin_amdgcn_mfma_f32_16x16x32_bf16(aL, pH, yacc, 0, 0, 0);
        }
        const int colL = lane & 15, rg = lane >> 4;
        const int col = ct * 16 + colL;
        const float bpv = bp[col];
#pragma unroll
        for (int i2 = 0; i2 < 4; ++i2) {
            const int row = rg * 4 + i2;
            out[(row0 + row) * 128 + col] = 1.0f / (1.0f + expf(-(yacc[i2] + bpv)));
        }
    }
}

extern "C" void kernel_launch(void* const* d_in, const int* in_sizes, int n_in,
                              void* d_out, int out_size, void* d_ws, size_t ws_size,
                              hipStream_t stream) {
    // setup_inputs order:
    // 0:x 1:adj 2:e_t 3:r_t 4:prev_h 5:W_heads 6:a_heads 7:W_out 8:a_out
    // 9:Wq_w 10:Wq_b 11:Wh_w 12:Wh_b 13:Wp_w 14:Wp_b
    const float* x      = (const float*)d_in[0];
    const float* e_t    = (const float*)d_in[2];
    const float* r_t    = (const float*)d_in[3];
    const float* prev_h = (const float*)d_in[4];
    const float* Wq_w   = (const float*)d_in[9];
    const float* Wq_b   = (const float*)d_in[10];
    const float* Wh_w   = (const float*)d_in[11];
    const float* Wh_b   = (const float*)d_in[12];
    const float* Wp_w   = (const float*)d_in[13];
    const float* Wp_b   = (const float*)d_in[14];
    float* out  = (float*)d_out;
    ushort* ws  = (ushort*)d_ws;   // 512 KB used

    hipLaunchKernelGGL(prep_w, dim3(256), dim3(64), 0, stream,
                       Wq_w, Wh_w, Wp_w, ws);
    hipLaunchKernelGGL(cekt_mfma, dim3(256), dim3(1024), 0, stream,
                       x, e_t, r_t, prev_h, Wq_b, Wh_b, Wp_b, ws, out);
}

// Round 8
// 18.846 us; speedup vs baseline: 2.2569x; 1.1012x over previous
//
#include <hip/hip_runtime.h>
#include <hip/hip_bf16.h>

// CEKT: y_t = sigmoid([h_t|e_t|x] @ Wp + bp)
//   h_t = (1-g)*prev_h + g*tanh(comb @ Wh + bh),  g = sigmoid(comb @ Wq + bq)
//   comb = [e_t | r_t | prev_h];  GAT branch is dead code w.r.t. y_t.
//
// Round-8: latency attack on the r7 structure.
//   - B-frag loads hoisted ACROSS barriers (compiler can't): phase1 first 3
//     ksteps prefetched before barrier1; kh1's phase2-static loads before
//     barrier2; kh0's phase2-remainder loads covered by the gate epilogue.
//   - h_t written directly in A2-frag layout from the epilogue (no hf buffer,
//     one barrier removed): 3 barriers total.
//   - prep_w: coalesced 64B-line loads (16-lane col groups), 4 elems/thread.

typedef short s16x8 __attribute__((ext_vector_type(8)));
typedef float f32x4 __attribute__((ext_vector_type(4)));

constexpr int NKQ = 10;  // K1=320 -> 10 ksteps of 32
constexpr int NKP = 12;  // K2=384 -> 12 ksteps of 32
constexpr int CH_Q = 0, CH_H = 80, CH_P = 160, NCHUNK = 256;
constexpr int LO_OFF = NCHUNK * 64;  // 16B units between hi and lo regions

__device__ __forceinline__ ushort bf16_rne(float f) {
    union { float f; uint u; } a; a.f = f;
    return (ushort)((a.u + 0x7FFFu + ((a.u >> 16) & 1u)) >> 16);
}
__device__ __forceinline__ float bf16_to_f(ushort h) {
    union { uint u; float f; } b; b.u = ((uint)h) << 16;
    return b.f;
}
__device__ __forceinline__ void split2(float f, ushort& hi, ushort& lo) {
    hi = bf16_rne(f);
    lo = bf16_rne(f - bf16_to_f(hi));
}

// ---------------- prep: weights -> B-frag hi/lo bf16 in d_ws ----------------
// frag elem (chunk, l, j):  W[s*32 + (l>>4)*8 + j][ct*16 + (l&15)]
// thread (jp,l) handles j = jp*4..jp*4+3; 16-lane groups read 16 consecutive
// cols at one k -> dense 64B lines.
__global__ __launch_bounds__(128) void prep_w(
    const float* __restrict__ Wq, const float* __restrict__ Wh,
    const float* __restrict__ Wp, ushort* __restrict__ ws)
{
    const int chunk = blockIdx.x;          // 0..255
    const int t = threadIdx.x;
    const int jp = t >> 6, l = t & 63;
    const float* W;
    int s, ct;
    if (chunk < CH_H)      { W = Wq; ct = chunk / NKQ;          s = chunk % NKQ; }
    else if (chunk < CH_P) { W = Wh; ct = (chunk - CH_H) / NKQ; s = (chunk - CH_H) % NKQ; }
    else                   { W = Wp; ct = (chunk - CH_P) / NKP; s = (chunk - CH_P) % NKP; }
    const int col = ct * 16 + (l & 15);
    const int kbase = s * 32 + (l >> 4) * 8 + jp * 4;
    ushort hi[4], lo[4];
#pragma unroll
    for (int j2 = 0; j2 < 4; ++j2)
        split2(W[(kbase + j2) * 128 + col], hi[j2], lo[j2]);
    const int ub = (chunk * 64 + l) * 8 + jp * 4;   // ushort offset
    *(uint2*)&ws[ub] = *(const uint2*)hi;
    *(uint2*)&ws[LO_OFF * 8 + ub] = *(const uint2*)lo;
}

// ---------------- main ----------------
__global__ __launch_bounds__(1024, 1) void cekt_mfma(
    const float* __restrict__ x,
    const float* __restrict__ e_t,
    const float* __restrict__ r_t,
    const float* __restrict__ prev_h,
    const float* __restrict__ bq,
    const float* __restrict__ bh,
    const float* __restrict__ bp,
    const ushort* __restrict__ ws,
    float* __restrict__ out)
{
    __shared__ alignas(16) ushort A1h[NKQ * 64 * 8], A1l[NKQ * 64 * 8];
    __shared__ alignas(16) ushort A2h[NKP * 64 * 8], A2l[NKP * 64 * 8];
    __shared__ f32x4 p1g[8][64], p1c[8][64], p2y[8][64];

    const int t = threadIdx.x;
    const int row0 = blockIdx.x * 16;
    const int w = t >> 6, lane = t & 63;
    const int ct = w & 7, kh = w >> 3;

    const s16x8* whv = (const s16x8*)ws;
    const s16x8* wlv = whv + LO_OFF;

    // ---- stage A1 (comb1), coalesced float4 per row ----
    for (int i = t; i < 1280; i += 1024) {
        const int row = i / 80, kq4 = i - row * 80;
        const int k0 = kq4 * 4;
        float4 v;
        if (k0 < 128)      v = *(const float4*)&e_t[(row0 + row) * 128 + k0];
        else if (k0 < 192) v = *(const float4*)&r_t[(row0 + row) * 64 + (k0 - 128)];
        else               v = *(const float4*)&prev_h[(row0 + row) * 128 + (k0 - 192)];
        const int s = k0 >> 5, q = (k0 >> 3) & 3, j0 = k0 & 7;
        const int base = (s * 64 + q * 16 + row) * 8 + j0;
        ushort hi4[4], lo4[4];
        split2(v.x, hi4[0], lo4[0]); split2(v.y, hi4[1], lo4[1]);
        split2(v.z, hi4[2], lo4[2]); split2(v.w, hi4[3], lo4[3]);
        *(uint2*)&A1h[base] = *(const uint2*)hi4;
        *(uint2*)&A1l[base] = *(const uint2*)lo4;
    }
    // ---- stage A2 static part (s=4..11: e_t | x), one float4 per thread ----
    {
        const int row = t >> 6, kr = t & 63;
        const int k0 = 128 + kr * 4;            // 128..380
        const float4 v = (k0 < 256)
            ? *(const float4*)&e_t[(row0 + row) * 128 + (k0 - 128)]
            : *(const float4*)&x[(row0 + row) * 128 + (k0 - 256)];
        const int s = k0 >> 5, q = (k0 >> 3) & 3, j0 = k0 & 7;
        const int base = (s * 64 + q * 16 + row) * 8 + j0;
        ushort hi4[4], lo4[4];
        split2(v.x, hi4[0], lo4[0]); split2(v.y, hi4[1], lo4[1]);
        split2(v.z, hi4[2], lo4[2]); split2(v.w, hi4[3], lo4[3]);
        *(uint2*)&A2h[base] = *(const uint2*)hi4;
        *(uint2*)&A2l[base] = *(const uint2*)lo4;
    }

    // ---- hoist: phase1 B loads for first 3 ksteps (prefetch across barrier)
    const int sbeg = kh * 5;
    s16x8 hqH[3], hqL[3], hcH[3], hcL[3];
#pragma unroll
    for (int si = 0; si < 3; ++si) {
        const int cq = (CH_Q + ct * NKQ + sbeg + si) * 64 + lane;
        const int cc = (CH_H + ct * NKQ + sbeg + si) * 64 + lane;
        hqH[si] = whv[cq]; hqL[si] = wlv[cq];
        hcH[si] = whv[cc]; hcL[si] = wlv[cc];
    }
    __syncthreads();                                        // barrier 1

    // ---- phase 1: g,cand partials over this k-half (5 ksteps) ----
    f32x4 gacc = {0, 0, 0, 0}, cacc = {0, 0, 0, 0};
#pragma unroll
    for (int si = 0; si < 5; ++si) {
        const int s = sbeg + si;
        const s16x8 aH = *(const s16x8*)&A1h[(s * 64 + lane) * 8];
        const s16x8 aL = *(const s16x8*)&A1l[(s * 64 + lane) * 8];
        s16x8 qH, qL, cH, cL;
        if (si < 3) { qH = hqH[si]; qL = hqL[si]; cH = hcH[si]; cL = hcL[si]; }
        else {
            const int cq = (CH_Q + ct * NKQ + s) * 64 + lane;
            const int cc = (CH_H + ct * NKQ + s) * 64 + lane;
            qH = whv[cq]; qL = wlv[cq]; cH = whv[cc]; cL = wlv[cc];
        }
        gacc = __builtin_amdgcn_mfma_f32_16x16x32_bf16(aH, qH, gacc, 0, 0, 0);
        cacc = __builtin_amdgcn_mfma_f32_16x16x32_bf16(aH, cH, cacc, 0, 0, 0);
        gacc = __builtin_amdgcn_mfma_f32_16x16x32_bf16(aH, qL, gacc, 0, 0, 0);
        cacc = __builtin_amdgcn_mfma_f32_16x16x32_bf16(aH, cL, cacc, 0, 0, 0);
        gacc = __builtin_amdgcn_mfma_f32_16x16x32_bf16(aL, qH, gacc, 0, 0, 0);
        cacc = __builtin_amdgcn_mfma_f32_16x16x32_bf16(aL, cH, cacc, 0, 0, 0);
    }

    // kh1: store partials, then prefetch phase2-static B loads across barrier2
    s16x8 pH[6], pL[6];
    if (kh) {
        p1g[ct][lane] = gacc;
        p1c[ct][lane] = cacc;
#pragma unroll
        for (int si = 0; si < 6; ++si) {
            const int cp = (CH_P + ct * NKP + 6 + si) * 64 + lane;
            pH[si] = whv[cp]; pL[si] = wlv[cp];
        }
    }
    __syncthreads();                                        // barrier 2

    f32x4 yacc = {0, 0, 0, 0};
    s16x8 rH[6], rL[6];
    if (!kh) {
        // issue phase2-remainder B loads first; epilogue VALU covers latency
#pragma unroll
        for (int si = 0; si < 6; ++si) {
            const int cp = (CH_P + ct * NKP + si) * 64 + lane;
            rH[si] = whv[cp]; rL[si] = wlv[cp];
        }
        // ---- reduce + gate epilogue; h_t written directly in A2-frag layout
        gacc += p1g[ct][lane];
        cacc += p1c[ct][lane];
        const int colL = lane & 15, rg = lane >> 4;
        const int col = ct * 16 + colL;
        const float bqv = bq[col], bhv = bh[col];
        const int s_h = col >> 5, q_h = (col >> 3) & 3, j_h = col & 7;
#pragma unroll
        for (int i2 = 0; i2 < 4; ++i2) {
            const int row = rg * 4 + i2;
            const float ph = prev_h[(row0 + row) * 128 + col];
            const float g = 1.0f / (1.0f + expf(-(gacc[i2] + bqv)));
            const float cd = tanhf(cacc[i2] + bhv);
            const float h = (1.0f - g) * ph + g * cd;
            ushort hh_, hl_;
            split2(h, hh_, hl_);
            const int idx = (s_h * 64 + q_h * 16 + row) * 8 + j_h;
            A2h[idx] = hh_;
            A2l[idx] = hl_;
        }
    } else {
        // ---- phase 2 partials over static ksteps s=6..11 (preloaded B) ----
#pragma unroll
        for (int si = 0; si < 6; ++si) {
            const int s = 6 + si;
            const s16x8 aH = *(const s16x8*)&A2h[(s * 64 + lane) * 8];
            const s16x8 aL = *(const s16x8*)&A2l[(s * 64 + lane) * 8];
            yacc = __builtin_amdgcn_mfma_f32_16x16x32_bf16(aH, pH[si], yacc, 0, 0, 0);
            yacc = __builtin_amdgcn_mfma_f32_16x16x32_bf16(aH, pL[si], yacc, 0, 0, 0);
            yacc = __builtin_amdgcn_mfma_f32_16x16x32_bf16(aL, pH[si], yacc, 0, 0, 0);
        }
        p2y[ct][lane] = yacc;
    }
    __syncthreads();                                        // barrier 3

    // ---- phase 2 remainder (s=0..5) + output, kh0 waves ----
    if (!kh) {
        yacc = p2y[ct][lane];
#pragma unroll
        for (int si = 0; si < 6; ++si) {
            const s16x8 aH = *(const s16x8*)&A2h[(si * 64 + lane) * 8];
            const s16x8 aL = *(const s16x8*)&A2l[(si * 64 + lane) * 8];
            yacc = __builtin_amdgcn_mfma_f32_16x16x32_bf16(aH, rH[si], yacc, 0, 0, 0);
            yacc = __builtin_amdgcn_mfma_f32_16x16x32_bf16(aH, rL[si], yacc, 0, 0, 0);
            yacc = __builtin_amdgcn_mfma_f32_16x16x32_bf16(aL, rH[si], yacc, 0, 0, 0);
        }
        const int colL = lane & 15, rg = lane >> 4;
        const int col = ct * 16 + colL;
        const float bpv = bp[col];
#pragma unroll
        for (int i2 = 0; i2 < 4; ++i2) {
            const int row = rg * 4 + i2;
            out[(row0 + row) * 128 + col] = 1.0f / (1.0f + expf(-(yacc[i2] + bpv)));
        }
    }
}

extern "C" void kernel_launch(void* const* d_in, const int* in_sizes, int n_in,
                              void* d_out, int out_size, void* d_ws, size_t ws_size,
                              hipStream_t stream) {
    // setup_inputs order:
    // 0:x 1:adj 2:e_t 3:r_t 4:prev_h 5:W_heads 6:a_heads 7:W_out 8:a_out
    // 9:Wq_w 10:Wq_b 11:Wh_w 12:Wh_b 13:Wp_w 14:Wp_b
    const float* x      = (const float*)d_in[0];
    const float* e_t    = (const float*)d_in[2];
    const float* r_t    = (const float*)d_in[3];
    const float* prev_h = (const float*)d_in[4];
    const float* Wq_w   = (const float*)d_in[9];
    const float* Wq_b   = (const float*)d_in[10];
    const float* Wh_w   = (const float*)d_in[11];
    const float* Wh_b   = (const float*)d_in[12];
    const float* Wp_w   = (const float*)d_in[13];
    const float* Wp_b   = (const float*)d_in[14];
    float* out  = (float*)d_out;
    ushort* ws  = (ushort*)d_ws;   // 512 KB used

    hipLaunchKernelGGL(prep_w, dim3(NCHUNK), dim3(128), 0, stream,
                       Wq_w, Wh_w, Wp_w, ws);
    hipLaunchKernelGGL(cekt_mfma, dim3(256), dim3(1024), 0, stream,
                       x, e_t, r_t, prev_h, Wq_b, Wh_b, Wp_b, ws, out);
}

// Round 9
// 17.110 us; speedup vs baseline: 2.4859x; 1.1015x over previous
//
#include <hip/hip_runtime.h>
#include <hip/hip_bf16.h>

// CEKT: y_t = sigmoid([h_t|e_t|x] @ Wp + bp)
//   h_t = (1-g)*prev_h + g*tanh(comb @ Wh + bh),  g = sigmoid(comb @ Wq + bq)
//   comb = [e_t | r_t | prev_h];  GAT branch is dead code w.r.t. y_t.
//
// Round-9: 2-term split-bf16 (drop the aH*wL term; W quantized to bf16 once):
//   x*w ~= xh*wh + xl*wh      (A-side hi/lo kept; W hi only)
// -> B traffic per CU halves (512->256 KB), B loads halve, MFMA -33%.
// All 5 phase-1 ksteps' B frags hoisted across barrier 1 (phase 1 has zero
// in-loop global loads). 3 barriers. prep writes hi only (256 KB).

typedef short s16x8 __attribute__((ext_vector_type(8)));
typedef float f32x4 __attribute__((ext_vector_type(4)));

constexpr int NKQ = 10;  // K1=320 -> 10 ksteps of 32
constexpr int NKP = 12;  // K2=384 -> 12 ksteps of 32
constexpr int CH_Q = 0, CH_H = 80, CH_P = 160, NCHUNK = 256;

__device__ __forceinline__ ushort bf16_rne(float f) {
    union { float f; uint u; } a; a.f = f;
    return (ushort)((a.u + 0x7FFFu + ((a.u >> 16) & 1u)) >> 16);
}
__device__ __forceinline__ float bf16_to_f(ushort h) {
    union { uint u; float f; } b; b.u = ((uint)h) << 16;
    return b.f;
}
__device__ __forceinline__ void split2(float f, ushort& hi, ushort& lo) {
    hi = bf16_rne(f);
    lo = bf16_rne(f - bf16_to_f(hi));
}

// ---------------- prep: weights -> B-frag bf16 (hi only) in d_ws ------------
// frag elem (chunk, l, j):  W[s*32 + (l>>4)*8 + j][ct*16 + (l&15)]
__global__ __launch_bounds__(128) void prep_w(
    const float* __restrict__ Wq, const float* __restrict__ Wh,
    const float* __restrict__ Wp, ushort* __restrict__ ws)
{
    const int chunk = blockIdx.x;          // 0..255
    const int t = threadIdx.x;
    const int jp = t >> 6, l = t & 63;
    const float* W;
    int s, ct;
    if (chunk < CH_H)      { W = Wq; ct = chunk / NKQ;          s = chunk % NKQ; }
    else if (chunk < CH_P) { W = Wh; ct = (chunk - CH_H) / NKQ; s = (chunk - CH_H) % NKQ; }
    else                   { W = Wp; ct = (chunk - CH_P) / NKP; s = (chunk - CH_P) % NKP; }
    const int col = ct * 16 + (l & 15);
    const int kbase = s * 32 + (l >> 4) * 8 + jp * 4;
    ushort hi[4];
#pragma unroll
    for (int j2 = 0; j2 < 4; ++j2)
        hi[j2] = bf16_rne(W[(kbase + j2) * 128 + col]);
    const int ub = (chunk * 64 + l) * 8 + jp * 4;   // ushort offset
    *(uint2*)&ws[ub] = *(const uint2*)hi;
}

// ---------------- main ----------------
__global__ __launch_bounds__(1024, 1) void cekt_mfma(
    const float* __restrict__ x,
    const float* __restrict__ e_t,
    const float* __restrict__ r_t,
    const float* __restrict__ prev_h,
    const float* __restrict__ bq,
    const float* __restrict__ bh,
    const float* __restrict__ bp,
    const ushort* __restrict__ ws,
    float* __restrict__ out)
{
    __shared__ alignas(16) ushort A1h[NKQ * 64 * 8], A1l[NKQ * 64 * 8];
    __shared__ alignas(16) ushort A2h[NKP * 64 * 8], A2l[NKP * 64 * 8];
    __shared__ f32x4 p1g[8][64], p1c[8][64], p2y[8][64];

    const int t = threadIdx.x;
    const int row0 = blockIdx.x * 16;
    const int w = t >> 6, lane = t & 63;
    const int ct = w & 7, kh = w >> 3;

    const s16x8* whv = (const s16x8*)ws;

    // ---- stage A1 (comb1), coalesced float4 per row ----
    for (int i = t; i < 1280; i += 1024) {
        const int row = i / 80, kq4 = i - row * 80;
        const int k0 = kq4 * 4;
        float4 v;
        if (k0 < 128)      v = *(const float4*)&e_t[(row0 + row) * 128 + k0];
        else if (k0 < 192) v = *(const float4*)&r_t[(row0 + row) * 64 + (k0 - 128)];
        else               v = *(const float4*)&prev_h[(row0 + row) * 128 + (k0 - 192)];
        const int s = k0 >> 5, q = (k0 >> 3) & 3, j0 = k0 & 7;
        const int base = (s * 64 + q * 16 + row) * 8 + j0;
        ushort hi4[4], lo4[4];
        split2(v.x, hi4[0], lo4[0]); split2(v.y, hi4[1], lo4[1]);
        split2(v.z, hi4[2], lo4[2]); split2(v.w, hi4[3], lo4[3]);
        *(uint2*)&A1h[base] = *(const uint2*)hi4;
        *(uint2*)&A1l[base] = *(const uint2*)lo4;
    }
    // ---- stage A2 static part (s=4..11: e_t | x), one float4 per thread ----
    {
        const int row = t >> 6, kr = t & 63;
        const int k0 = 128 + kr * 4;            // 128..380
        const float4 v = (k0 < 256)
            ? *(const float4*)&e_t[(row0 + row) * 128 + (k0 - 128)]
            : *(const float4*)&x[(row0 + row) * 128 + (k0 - 256)];
        const int s = k0 >> 5, q = (k0 >> 3) & 3, j0 = k0 & 7;
        const int base = (s * 64 + q * 16 + row) * 8 + j0;
        ushort hi4[4], lo4[4];
        split2(v.x, hi4[0], lo4[0]); split2(v.y, hi4[1], lo4[1]);
        split2(v.z, hi4[2], lo4[2]); split2(v.w, hi4[3], lo4[3]);
        *(uint2*)&A2h[base] = *(const uint2*)hi4;
        *(uint2*)&A2l[base] = *(const uint2*)lo4;
    }

    // ---- hoist: ALL phase1 B frags (hi only, 5 ksteps x {q,c}) ----
    const int sbeg = kh * 5;
    s16x8 hq[5], hc[5];
#pragma unroll
    for (int si = 0; si < 5; ++si) {
        const int cq = (CH_Q + ct * NKQ + sbeg + si) * 64 + lane;
        const int cc = (CH_H + ct * NKQ + sbeg + si) * 64 + lane;
        hq[si] = whv[cq];
        hc[si] = whv[cc];
    }
    __syncthreads();                                        // barrier 1

    // ---- phase 1: g,cand partials, pure LDS+MFMA (B preloaded) ----
    f32x4 gacc = {0, 0, 0, 0}, cacc = {0, 0, 0, 0};
#pragma unroll
    for (int si = 0; si < 5; ++si) {
        const int s = sbeg + si;
        const s16x8 aH = *(const s16x8*)&A1h[(s * 64 + lane) * 8];
        const s16x8 aL = *(const s16x8*)&A1l[(s * 64 + lane) * 8];
        gacc = __builtin_amdgcn_mfma_f32_16x16x32_bf16(aH, hq[si], gacc, 0, 0, 0);
        cacc = __builtin_amdgcn_mfma_f32_16x16x32_bf16(aH, hc[si], cacc, 0, 0, 0);
        gacc = __builtin_amdgcn_mfma_f32_16x16x32_bf16(aL, hq[si], gacc, 0, 0, 0);
        cacc = __builtin_amdgcn_mfma_f32_16x16x32_bf16(aL, hc[si], cacc, 0, 0, 0);
    }

    // kh1: store partials, then prefetch phase2-static B across barrier2
    s16x8 pH[6];
    if (kh) {
        p1g[ct][lane] = gacc;
        p1c[ct][lane] = cacc;
#pragma unroll
        for (int si = 0; si < 6; ++si)
            pH[si] = whv[(CH_P + ct * NKP + 6 + si) * 64 + lane];
    }
    __syncthreads();                                        // barrier 2

    f32x4 yacc = {0, 0, 0, 0};
    s16x8 rH[6];
    if (!kh) {
        // issue phase2-remainder B loads first; epilogue VALU covers latency
#pragma unroll
        for (int si = 0; si < 6; ++si)
            rH[si] = whv[(CH_P + ct * NKP + si) * 64 + lane];
        // ---- reduce + gate epilogue; h_t written directly in A2-frag layout
        gacc += p1g[ct][lane];
        cacc += p1c[ct][lane];
        const int colL = lane & 15, rg = lane >> 4;
        const int col = ct * 16 + colL;
        const float bqv = bq[col], bhv = bh[col];
        const int s_h = col >> 5, q_h = (col >> 3) & 3, j_h = col & 7;
#pragma unroll
        for (int i2 = 0; i2 < 4; ++i2) {
            const int row = rg * 4 + i2;
            const float ph = prev_h[(row0 + row) * 128 + col];
            const float g = 1.0f / (1.0f + expf(-(gacc[i2] + bqv)));
            const float cd = tanhf(cacc[i2] + bhv);
            const float h = (1.0f - g) * ph + g * cd;
            ushort hh_, hl_;
            split2(h, hh_, hl_);
            const int idx = (s_h * 64 + q_h * 16 + row) * 8 + j_h;
            A2h[idx] = hh_;
            A2l[idx] = hl_;
        }
    } else {
        // ---- phase 2 partials over static ksteps s=6..11 (preloaded B) ----
#pragma unroll
        for (int si = 0; si < 6; ++si) {
            const int s = 6 + si;
            const s16x8 aH = *(const s16x8*)&A2h[(s * 64 + lane) * 8];
            const s16x8 aL = *(const s16x8*)&A2l[(s * 64 + lane) * 8];
            yacc = __builtin_amdgcn_mfma_f32_16x16x32_bf16(aH, pH[si], yacc, 0, 0, 0);
            yacc = __builtin_amdgcn_mfma_f32_16x16x32_bf16(aL, pH[si], yacc, 0, 0, 0);
        }
        p2y[ct][lane] = yacc;
    }
    __syncthreads();                                        // barrier 3

    // ---- phase 2 remainder (s=0..5, contains h_t) + output, kh0 waves ----
    if (!kh) {
        yacc = p2y[ct][lane];
#pragma unroll
        for (int si = 0; si < 6; ++si) {
            const s16x8 aH = *(const s16x8*)&A2h[(si * 64 + lane) * 8];
            const s16x8 aL = *(const s16x8*)&A2l[(si * 64 + lane) * 8];
            yacc = __builtin_amdgcn_mfma_f32_16x16x32_bf16(aH, rH[si], yacc, 0, 0, 0);
            yacc = __builtin_amdgcn_mfma_f32_16x16x32_bf16(aL, rH[si], yacc, 0, 0, 0);
        }
        const int colL = lane & 15, rg = lane >> 4;
        const int col = ct * 16 + colL;
        const float bpv = bp[col];
#pragma unroll
        for (int i2 = 0; i2 < 4; ++i2) {
            const int row = rg * 4 + i2;
            out[(row0 + row) * 128 + col] = 1.0f / (1.0f + expf(-(yacc[i2] + bpv)));
        }
    }
}

extern "C" void kernel_launch(void* const* d_in, const int* in_sizes, int n_in,
                              void* d_out, int out_size, void* d_ws, size_t ws_size,
                              hipStream_t stream) {
    // setup_inputs order:
    // 0:x 1:adj 2:e_t 3:r_t 4:prev_h 5:W_heads 6:a_heads 7:W_out 8:a_out
    // 9:Wq_w 10:Wq_b 11:Wh_w 12:Wh_b 13:Wp_w 14:Wp_b
    const float* x      = (const float*)d_in[0];
    const float* e_t    = (const float*)d_in[2];
    const float* r_t    = (const float*)d_in[3];
    const float* prev_h = (const float*)d_in[4];
    const float* Wq_w   = (const float*)d_in[9];
    const float* Wq_b   = (const float*)d_in[10];
    const float* Wh_w   = (const float*)d_in[11];
    const float* Wh_b   = (const float*)d_in[12];
    const float* Wp_w   = (const float*)d_in[13];
    const float* Wp_b   = (const float*)d_in[14];
    float* out  = (float*)d_out;
    ushort* ws  = (ushort*)d_ws;   // 256 KB used

    hipLaunchKernelGGL(prep_w, dim3(NCHUNK), dim3(128), 0, stream,
                       Wq_w, Wh_w, Wp_w, ws);
    hipLaunchKernelGGL(cekt_mfma, dim3(256), dim3(1024), 0, stream,
                       x, e_t, r_t, prev_h, Wq_b, Wh_b, Wp_b, ws, out);
}